// Round 1
// baseline (294.490 us; speedup 1.0000x reference)
//
#include <hip/hip_runtime.h>
#include <math.h>

#define NQ 7
#define NL 6
#define BATCH 8192
#define NPCA 32
#define NCLS 3129
#define NGATE 42

// ---------------------------------------------------------------------------
// Quantum circuit: one wave (64 lanes) per sample. Lane l holds amplitudes
// 2l (slot0) and 2l+1 (slot1) as (re,im) pairs in registers.
// Bit b = NQ-1-q of the 7-bit state index selects the qubit-q axis.
//   b==0  -> slot bit (within-lane pair)
//   b>=1  -> lane bit (b-1) (cross-lane via shfl_xor)
// Fused: Z-expectations (7) + q-head layer1 (64 outputs, lane j -> col j).
// ---------------------------------------------------------------------------
__global__ __launch_bounds__(256) void quantum_kernel(
    const float* __restrict__ x,       // B x 32
    const float* __restrict__ fscale,  // 32
    const float* __restrict__ qw,      // 6 x 7 x 2
    const float* __restrict__ qh_w1,   // 7 x 64
    const float* __restrict__ qh_b1,   // 64
    float* __restrict__ qf_out,        // B x 7
    float* __restrict__ hq_out)        // B x 64
{
    __shared__ float pzc[NGATE], pzs[NGATE], w0s[NGATE];
    int tid = threadIdx.x;
    if (tid < NGATE) {
        float t = qw[tid * 2 + 1] * 0.5f;   // RZ angles are batch-invariant
        float s, c;
        sincosf(t, &s, &c);
        pzs[tid] = s; pzc[tid] = c;
        w0s[tid] = qw[tid * 2 + 0];
    }
    __syncthreads();

    const int lane = tid & 63;
    const int wave = tid >> 6;
    const int sample = blockIdx.x * 4 + wave;

    float myfeat = 0.f;
    if (lane < NPCA) myfeat = atanf(x[sample * NPCA + lane] * fscale[lane]);

    float s0r = (lane == 0) ? 1.f : 0.f, s0i = 0.f, s1r = 0.f, s1i = 0.f;

    for (int layer = 0; layer < NL; ++layer) {
        for (int q = 0; q < NQ; ++q) {
            const int g = layer * NQ + q;
            const int b = NQ - 1 - q;
            // ---- RY(feats[g] + w0[g]) ----
            float fv = (g < NPCA) ? __shfl(myfeat, g) : 0.f;
            float th = (fv + w0s[g]) * 0.5f;
            float s, c;
            sincosf(th, &s, &c);
            if (b == 0) {
                float n0r = c * s0r - s * s1r, n0i = c * s0i - s * s1i;
                float n1r = s * s0r + c * s1r, n1i = s * s0i + c * s1i;
                s0r = n0r; s0i = n0i; s1r = n1r; s1i = n1i;
            } else {
                int m = 1 << (b - 1);
                float p0r = __shfl_xor(s0r, m), p0i = __shfl_xor(s0i, m);
                float p1r = __shfl_xor(s1r, m), p1i = __shfl_xor(s1i, m);
                if (((lane >> (b - 1)) & 1) == 0) {  // own = a0, partner = a1
                    s0r = c * s0r - s * p0r; s0i = c * s0i - s * p0i;
                    s1r = c * s1r - s * p1r; s1i = c * s1i - s * p1i;
                } else {                              // own = a1, partner = a0
                    s0r = s * p0r + c * s0r; s0i = s * p0i + c * s0i;
                    s1r = s * p1r + c * s1r; s1i = s * p1i + c * s1i;
                }
            }
            // ---- RZ(w1[g]): amp *= (pc - i*ps) if bit==0 else (pc + i*ps) ----
            float pc = pzc[g], ps = pzs[g];
            if (b == 0) {
                float t0 = pc * s0r + ps * s0i; s0i = pc * s0i - ps * s0r; s0r = t0;
                float t1 = pc * s1r - ps * s1i; s1i = pc * s1i + ps * s1r; s1r = t1;
            } else {
                float e = (((lane >> (b - 1)) & 1) == 0) ? ps : -ps;
                float t0 = pc * s0r + e * s0i; s0i = pc * s0i - e * s0r; s0r = t0;
                float t1 = pc * s1r + e * s1i; s1i = pc * s1i - e * s1r; s1r = t1;
            }
        }
        // ---- CNOT ring: q = control, (q+1)%7 = target, applied sequentially ----
        #pragma unroll
        for (int cq = 0; cq < NQ; ++cq) {
            if (cq == NQ - 1) {
                // control = slot bit, target = lane bit 5: slot1 swaps lanes l <-> l^32
                float r = __shfl_xor(s1r, 32), im = __shfl_xor(s1i, 32);
                s1r = r; s1i = im;
            } else if (cq == NQ - 2) {
                // control = lane bit 0, target = slot bit: odd lanes swap slots
                if (lane & 1) {
                    float tr = s0r; s0r = s1r; s1r = tr;
                    float ti = s0i; s0i = s1i; s1i = ti;
                }
            } else {
                const int bc = NQ - 1 - cq;      // control bit (lane bit bc-1)
                const int bt = bc - 1;           // target bit  (lane bit bt-1)
                int m = 1 << (bt - 1);
                float p0r = __shfl_xor(s0r, m), p0i = __shfl_xor(s0i, m);
                float p1r = __shfl_xor(s1r, m), p1i = __shfl_xor(s1i, m);
                if ((lane >> (bc - 1)) & 1) {
                    s0r = p0r; s0i = p0i; s1r = p1r; s1i = p1i;
                }
            }
        }
    }

    // ---- probs -> Z expectations ----
    float p0 = s0r * s0r + s0i * s0i;
    float p1 = s1r * s1r + s1i * s1i;
    float psum = p0 + p1;
    float qf[7];
    #pragma unroll
    for (int k = 0; k < 6; ++k)
        qf[k] = (((lane >> (5 - k)) & 1) ? -psum : psum);  // bit 6-k of idx = lane bit 5-k
    qf[6] = p0 - p1;                                        // bit 0 = slot
    #pragma unroll
    for (int off = 32; off >= 1; off >>= 1) {
        #pragma unroll
        for (int k = 0; k < 7; ++k) qf[k] += __shfl_xor(qf[k], off);
    }

    // ---- fused q-head layer 1: lane j computes relu(qf . w1[:,j] + b1[j]) ----
    float acc = qh_b1[lane];
    #pragma unroll
    for (int k = 0; k < 7; ++k) acc += qf[k] * qh_w1[k * 64 + lane];
    hq_out[sample * 64 + lane] = fmaxf(acc, 0.f);
    if (lane < 7) qf_out[sample * 7 + lane] = qf[lane];
}

// ---------------------------------------------------------------------------
// Classical head layers 1+2 fused: 32 rows/block, h1 (32x256) kept in LDS.
// ---------------------------------------------------------------------------
__global__ __launch_bounds__(256) void chead_kernel(
    const float* __restrict__ x,    // B x 32
    const float* __restrict__ w1,   // 32 x 256
    const float* __restrict__ b1,   // 256
    const float* __restrict__ w2,   // 256 x 128
    const float* __restrict__ b2,   // 128
    float* __restrict__ h2out)      // B x 128
{
    __shared__ float xs[32][36];
    __shared__ float h1s[32][260];
    const int tid = threadIdx.x;
    const int row0 = blockIdx.x * 32;

    for (int i = tid; i < 32 * 32; i += 256) {
        int r = i >> 5, k = i & 31;
        xs[r][k] = x[(row0 + r) * 32 + k];
    }
    __syncthreads();

    // layer 1: thread -> column tid
    {
        float w1c[32];
        #pragma unroll
        for (int k = 0; k < 32; ++k) w1c[k] = w1[k * 256 + tid];
        float bb = b1[tid];
        for (int r = 0; r < 32; ++r) {
            float acc = bb;
            #pragma unroll
            for (int k = 0; k < 32; ++k) acc += xs[r][k] * w1c[k];
            h1s[r][tid] = fmaxf(acc, 0.f);
        }
    }
    __syncthreads();

    // layer 2: thread -> 8 rows x 2 cols
    {
        const int c0 = (tid & 63) * 2;
        const int r0 = (tid >> 6) * 8;
        float accA[8], accB[8];
        float bbA = b2[c0], bbB = b2[c0 + 1];
        #pragma unroll
        for (int rr = 0; rr < 8; ++rr) { accA[rr] = bbA; accB[rr] = bbB; }
        for (int k = 0; k < 256; k += 4) {
            float hb[8][4];
            #pragma unroll
            for (int rr = 0; rr < 8; ++rr) {
                float4 h4 = *(const float4*)&h1s[r0 + rr][k];
                hb[rr][0] = h4.x; hb[rr][1] = h4.y; hb[rr][2] = h4.z; hb[rr][3] = h4.w;
            }
            #pragma unroll
            for (int j = 0; j < 4; ++j) {
                float2 w = *(const float2*)&w2[(k + j) * 128 + c0];
                #pragma unroll
                for (int rr = 0; rr < 8; ++rr) {
                    accA[rr] += hb[rr][j] * w.x;
                    accB[rr] += hb[rr][j] * w.y;
                }
            }
        }
        #pragma unroll
        for (int rr = 0; rr < 8; ++rr) {
            h2out[(row0 + r0 + rr) * 128 + c0]     = fmaxf(accA[rr], 0.f);
            h2out[(row0 + r0 + rr) * 128 + c0 + 1] = fmaxf(accB[rr], 0.f);
        }
    }
}

// ---------------------------------------------------------------------------
// Big skinny GEMM: C(MxN) = A(MxK) @ B(KxN) + bias. 64x64 tile, 256 threads,
// 4x4 micro-tile per thread. A staged transposed in LDS for float4 reads.
// N odd (3129) -> scalar B loads with column guard.
// ---------------------------------------------------------------------------
template <int K>
__global__ __launch_bounds__(256) void gemm_big(
    const float* __restrict__ A,    // M x K
    const float* __restrict__ Bm,   // K x N
    const float* __restrict__ bias, // N
    float* __restrict__ C,          // M x N
    int M, int N)
{
    constexpr int KB = 64;
    static_assert(K % KB == 0, "K must be multiple of 64");
    __shared__ float Ast[KB][64 + 4];  // [k][r]
    __shared__ float Bs[KB][64 + 4];   // [k][c]

    const int tid = threadIdx.x;
    const int tx = tid & 15;     // col group
    const int ty = tid >> 4;     // row group
    const int col0 = blockIdx.x * 64;
    const int row0 = blockIdx.y * 64;

    float acc[4][4] = {};

    for (int kb = 0; kb < K; kb += KB) {
        // stage A (64 rows x 64 k), transposed into LDS
        #pragma unroll
        for (int i = 0; i < 4; ++i) {
            int idx = tid + i * 256;          // 0..1023 float4 slots
            int r = idx >> 4;                  // 0..63
            int kc = (idx & 15) << 2;          // 0..60
            float4 v = *(const float4*)&A[(size_t)(row0 + r) * K + kb + kc];
            Ast[kc + 0][r] = v.x; Ast[kc + 1][r] = v.y;
            Ast[kc + 2][r] = v.z; Ast[kc + 3][r] = v.w;
        }
        // stage B (64 k x 64 cols), scalar (N odd)
        #pragma unroll
        for (int i = 0; i < 16; ++i) {
            int idx = tid + i * 256;
            int kr = idx >> 6, c = idx & 63;
            int col = col0 + c;
            Bs[kr][c] = (col < N) ? Bm[(size_t)(kb + kr) * N + col] : 0.f;
        }
        __syncthreads();

        #pragma unroll 8
        for (int k = 0; k < KB; ++k) {
            float4 a4 = *(const float4*)&Ast[k][ty * 4];
            float4 b4 = *(const float4*)&Bs[k][tx * 4];
            acc[0][0] += a4.x * b4.x; acc[0][1] += a4.x * b4.y;
            acc[0][2] += a4.x * b4.z; acc[0][3] += a4.x * b4.w;
            acc[1][0] += a4.y * b4.x; acc[1][1] += a4.y * b4.y;
            acc[1][2] += a4.y * b4.z; acc[1][3] += a4.y * b4.w;
            acc[2][0] += a4.z * b4.x; acc[2][1] += a4.z * b4.y;
            acc[2][2] += a4.z * b4.z; acc[2][3] += a4.z * b4.w;
            acc[3][0] += a4.w * b4.x; acc[3][1] += a4.w * b4.y;
            acc[3][2] += a4.w * b4.z; acc[3][3] += a4.w * b4.w;
        }
        __syncthreads();
    }

    #pragma unroll
    for (int i = 0; i < 4; ++i) {
        int row = row0 + ty * 4 + i;
        #pragma unroll
        for (int j = 0; j < 4; ++j) {
            int col = col0 + tx * 4 + j;
            if (col < N) C[(size_t)row * N + col] = acc[i][j] + bias[col];
        }
    }
}

extern "C" void kernel_launch(void* const* d_in, const int* in_sizes, int n_in,
                              void* d_out, int out_size, void* d_ws, size_t ws_size,
                              hipStream_t stream)
{
    const float* x   = (const float*)d_in[0];
    const float* fs  = (const float*)d_in[1];
    const float* qw  = (const float*)d_in[2];
    const float* qw1 = (const float*)d_in[3];
    const float* qb1 = (const float*)d_in[4];
    const float* qw2 = (const float*)d_in[5];
    const float* qb2 = (const float*)d_in[6];
    const float* cw1 = (const float*)d_in[7];
    const float* cb1 = (const float*)d_in[8];
    const float* cw2 = (const float*)d_in[9];
    const float* cb2 = (const float*)d_in[10];
    const float* cw3 = (const float*)d_in[11];
    const float* cb3 = (const float*)d_in[12];

    float* q_logits = (float*)d_out;
    float* c_logits = q_logits + (size_t)BATCH * NCLS;
    float* qf_out   = c_logits + (size_t)BATCH * NCLS;

    float* hq = (float*)d_ws;                  // 8192 x 64  (2 MB)
    float* h2 = hq + (size_t)BATCH * 64;       // 8192 x 128 (4 MB)

    quantum_kernel<<<BATCH / 4, 256, 0, stream>>>(x, fs, qw, qw1, qb1, qf_out, hq);
    chead_kernel<<<BATCH / 32, 256, 0, stream>>>(x, cw1, cb1, cw2, cb2, h2);

    dim3 grid((NCLS + 63) / 64, BATCH / 64);
    gemm_big<64><<<grid, 256, 0, stream>>>(hq, qw2, qb2, q_logits, BATCH, NCLS);
    gemm_big<128><<<grid, 256, 0, stream>>>(h2, cw3, cb3, c_logits, BATCH, NCLS);
}

// Round 2
// 170.370 us; speedup vs baseline: 1.7285x; 1.7285x over previous
//
#include <hip/hip_runtime.h>
#include <hip/hip_bf16.h>
#include <math.h>

#define NQ 7
#define NL 6
#define BATCH 8192
#define NPCA 32
#define NCLS 3129
#define NGATE 42

typedef __attribute__((ext_vector_type(8))) short short8;
typedef __attribute__((ext_vector_type(4))) float f32x4;

// ---------------------------------------------------------------------------
// Quantum circuit: one wave per sample, 2 complex amps per lane (registers).
// Fused: Z-expectations + q-head layer1 (relu(qf@W1+b1)) -> bf16.
// ---------------------------------------------------------------------------
__global__ __launch_bounds__(256) void quantum_kernel(
    const float* __restrict__ x,       // B x 32
    const float* __restrict__ fscale,  // 32
    const float* __restrict__ qw,      // 6 x 7 x 2
    const float* __restrict__ qh_w1,   // 7 x 64
    const float* __restrict__ qh_b1,   // 64
    float* __restrict__ qf_out,        // B x 7 (fp32, part of d_out)
    __hip_bfloat16* __restrict__ hq_out) // B x 64 bf16
{
    __shared__ float pzc[NGATE], pzs[NGATE], w0s[NGATE];
    int tid = threadIdx.x;
    if (tid < NGATE) {
        float t = qw[tid * 2 + 1] * 0.5f;
        float s, c;
        sincosf(t, &s, &c);
        pzs[tid] = s; pzc[tid] = c;
        w0s[tid] = qw[tid * 2 + 0];
    }
    __syncthreads();

    const int lane = tid & 63;
    const int wave = tid >> 6;
    const int sample = blockIdx.x * 4 + wave;

    float myfeat = 0.f;
    if (lane < NPCA) myfeat = atanf(x[sample * NPCA + lane] * fscale[lane]);

    float s0r = (lane == 0) ? 1.f : 0.f, s0i = 0.f, s1r = 0.f, s1i = 0.f;

    for (int layer = 0; layer < NL; ++layer) {
        for (int q = 0; q < NQ; ++q) {
            const int g = layer * NQ + q;
            const int b = NQ - 1 - q;
            float fv = (g < NPCA) ? __shfl(myfeat, g) : 0.f;
            float th = (fv + w0s[g]) * 0.5f;
            float s, c;
            sincosf(th, &s, &c);
            if (b == 0) {
                float n0r = c * s0r - s * s1r, n0i = c * s0i - s * s1i;
                float n1r = s * s0r + c * s1r, n1i = s * s0i + c * s1i;
                s0r = n0r; s0i = n0i; s1r = n1r; s1i = n1i;
            } else {
                int m = 1 << (b - 1);
                float p0r = __shfl_xor(s0r, m), p0i = __shfl_xor(s0i, m);
                float p1r = __shfl_xor(s1r, m), p1i = __shfl_xor(s1i, m);
                if (((lane >> (b - 1)) & 1) == 0) {
                    s0r = c * s0r - s * p0r; s0i = c * s0i - s * p0i;
                    s1r = c * s1r - s * p1r; s1i = c * s1i - s * p1i;
                } else {
                    s0r = s * p0r + c * s0r; s0i = s * p0i + c * s0i;
                    s1r = s * p1r + c * s1r; s1i = s * p1i + c * s1i;
                }
            }
            float pc = pzc[g], ps = pzs[g];
            if (b == 0) {
                float t0 = pc * s0r + ps * s0i; s0i = pc * s0i - ps * s0r; s0r = t0;
                float t1 = pc * s1r - ps * s1i; s1i = pc * s1i + ps * s1r; s1r = t1;
            } else {
                float e = (((lane >> (b - 1)) & 1) == 0) ? ps : -ps;
                float t0 = pc * s0r + e * s0i; s0i = pc * s0i - e * s0r; s0r = t0;
                float t1 = pc * s1r + e * s1i; s1i = pc * s1i - e * s1r; s1r = t1;
            }
        }
        #pragma unroll
        for (int cq = 0; cq < NQ; ++cq) {
            if (cq == NQ - 1) {
                float r = __shfl_xor(s1r, 32), im = __shfl_xor(s1i, 32);
                s1r = r; s1i = im;
            } else if (cq == NQ - 2) {
                if (lane & 1) {
                    float tr = s0r; s0r = s1r; s1r = tr;
                    float ti = s0i; s0i = s1i; s1i = ti;
                }
            } else {
                const int bc = NQ - 1 - cq;
                const int bt = bc - 1;
                int m = 1 << (bt - 1);
                float p0r = __shfl_xor(s0r, m), p0i = __shfl_xor(s0i, m);
                float p1r = __shfl_xor(s1r, m), p1i = __shfl_xor(s1i, m);
                if ((lane >> (bc - 1)) & 1) {
                    s0r = p0r; s0i = p0i; s1r = p1r; s1i = p1i;
                }
            }
        }
    }

    float p0 = s0r * s0r + s0i * s0i;
    float p1 = s1r * s1r + s1i * s1i;
    float psum = p0 + p1;
    float qf[7];
    #pragma unroll
    for (int k = 0; k < 6; ++k)
        qf[k] = (((lane >> (5 - k)) & 1) ? -psum : psum);
    qf[6] = p0 - p1;
    #pragma unroll
    for (int off = 32; off >= 1; off >>= 1) {
        #pragma unroll
        for (int k = 0; k < 7; ++k) qf[k] += __shfl_xor(qf[k], off);
    }

    float acc = qh_b1[lane];
    #pragma unroll
    for (int k = 0; k < 7; ++k) acc += qf[k] * qh_w1[k * 64 + lane];
    hq_out[sample * 64 + lane] = __float2bfloat16(fmaxf(acc, 0.f));
    if (lane < 7) qf_out[sample * 7 + lane] = qf[lane];
}

// ---------------------------------------------------------------------------
// Classical head layers 1+2 fused -> h2 bf16.
// ---------------------------------------------------------------------------
__global__ __launch_bounds__(256) void chead_kernel(
    const float* __restrict__ x,    // B x 32
    const float* __restrict__ w1,   // 32 x 256
    const float* __restrict__ b1,   // 256
    const float* __restrict__ w2,   // 256 x 128
    const float* __restrict__ b2,   // 128
    __hip_bfloat16* __restrict__ h2out) // B x 128 bf16
{
    __shared__ float xs[32][36];
    __shared__ float h1s[32][260];
    const int tid = threadIdx.x;
    const int row0 = blockIdx.x * 32;

    for (int i = tid; i < 32 * 32; i += 256) {
        int r = i >> 5, k = i & 31;
        xs[r][k] = x[(row0 + r) * 32 + k];
    }
    __syncthreads();

    {
        float w1c[32];
        #pragma unroll
        for (int k = 0; k < 32; ++k) w1c[k] = w1[k * 256 + tid];
        float bb = b1[tid];
        for (int r = 0; r < 32; ++r) {
            float acc = bb;
            #pragma unroll
            for (int k = 0; k < 32; ++k) acc += xs[r][k] * w1c[k];
            h1s[r][tid] = fmaxf(acc, 0.f);
        }
    }
    __syncthreads();

    {
        const int c0 = (tid & 63) * 2;
        const int r0 = (tid >> 6) * 8;
        float accA[8], accB[8];
        float bbA = b2[c0], bbB = b2[c0 + 1];
        #pragma unroll
        for (int rr = 0; rr < 8; ++rr) { accA[rr] = bbA; accB[rr] = bbB; }
        for (int k = 0; k < 256; k += 4) {
            float hb[8][4];
            #pragma unroll
            for (int rr = 0; rr < 8; ++rr) {
                float4 h4 = *(const float4*)&h1s[r0 + rr][k];
                hb[rr][0] = h4.x; hb[rr][1] = h4.y; hb[rr][2] = h4.z; hb[rr][3] = h4.w;
            }
            #pragma unroll
            for (int j = 0; j < 4; ++j) {
                float2 w = *(const float2*)&w2[(k + j) * 128 + c0];
                #pragma unroll
                for (int rr = 0; rr < 8; ++rr) {
                    accA[rr] += hb[rr][j] * w.x;
                    accB[rr] += hb[rr][j] * w.y;
                }
            }
        }
        #pragma unroll
        for (int rr = 0; rr < 8; ++rr) {
            __hip_bfloat162 pr;
            pr.x = __float2bfloat16(fmaxf(accA[rr], 0.f));
            pr.y = __float2bfloat16(fmaxf(accB[rr], 0.f));
            *(__hip_bfloat162*)&h2out[(size_t)(row0 + r0 + rr) * 128 + c0] = pr;
        }
    }
}

// ---------------------------------------------------------------------------
// Weight prep: W (K x N fp32) -> Wt (N x K bf16). Tiny (~600K elems); reads
// coalesced, 2B scattered writes absorbed by L2 (800 KB total footprint).
// ---------------------------------------------------------------------------
__global__ __launch_bounds__(256) void transpose_cast(
    const float* __restrict__ W, __hip_bfloat16* __restrict__ Wt, int K, int N)
{
    int idx = blockIdx.x * 256 + threadIdx.x;
    if (idx >= K * N) return;
    int k = idx / N, n = idx - k * N;
    Wt[n * K + k] = __float2bfloat16(W[idx]);
}

// ---------------------------------------------------------------------------
// MFMA GEMM: C(MxN) = A(MxK) @ Bt(NxK)^T + bias. 128x128 tile, 4 waves
// (each 64x64 = 4x4 fragments of 16x16), KB=64 LDS staging, +8 bf16 row pad
// (bank = 4*(r+ks) mod 32 -> even 8 accesses/bank, conflict-free b128 reads).
// ---------------------------------------------------------------------------
template <int K>
__global__ __launch_bounds__(256) void gemm_mfma(
    const __hip_bfloat16* __restrict__ A,   // M x K bf16
    const __hip_bfloat16* __restrict__ Bt,  // N x K bf16
    const float* __restrict__ bias,         // N
    float* __restrict__ C,                  // M x N fp32
    int N)
{
    constexpr int KB = 64;
    constexpr int LDK = KB + 8;  // 72 bf16 = 144 B row stride
    static_assert(K % KB == 0, "");
    __shared__ __hip_bfloat16 Alds[128 * LDK];
    __shared__ __hip_bfloat16 Blds[128 * LDK];

    const int tid  = threadIdx.x;
    const int lane = tid & 63;
    const int wave = tid >> 6;
    const int wr = wave >> 1, wc = wave & 1;       // 2x2 waves -> 64x64 each
    const int row0 = blockIdx.y * 128;
    const int col0 = blockIdx.x * 128;

    f32x4 acc[4][4] = {};

    for (int kb = 0; kb < K; kb += KB) {
        // stage A: 128 rows x 64 bf16; 1024 16B-chunks over 256 threads
        #pragma unroll
        for (int i = 0; i < 4; ++i) {
            int ch = tid + i * 256;
            int r = ch >> 3;              // 0..127
            int kc = (ch & 7) << 3;       // 0..56
            float4 v = *(const float4*)&A[(size_t)(row0 + r) * K + kb + kc];
            *(float4*)&Alds[r * LDK + kc] = v;
        }
        // stage B: 128 n-rows x 64 bf16 from Bt, zero-fill n >= N
        #pragma unroll
        for (int i = 0; i < 4; ++i) {
            int ch = tid + i * 256;
            int r = ch >> 3;
            int kc = (ch & 7) << 3;
            int n = col0 + r;
            float4 v = make_float4(0.f, 0.f, 0.f, 0.f);
            if (n < N) v = *(const float4*)&Bt[(size_t)n * K + kb + kc];
            *(float4*)&Blds[r * LDK + kc] = v;
        }
        __syncthreads();

        const int frow = lane & 15;
        const int koff = (lane >> 4) << 3;
        #pragma unroll
        for (int kk = 0; kk < KB; kk += 32) {
            short8 af[4], bf[4];
            #pragma unroll
            for (int m = 0; m < 4; ++m)
                af[m] = *(const short8*)&Alds[(wr * 64 + m * 16 + frow) * LDK + kk + koff];
            #pragma unroll
            for (int n = 0; n < 4; ++n)
                bf[n] = *(const short8*)&Blds[(wc * 64 + n * 16 + frow) * LDK + kk + koff];
            #pragma unroll
            for (int m = 0; m < 4; ++m)
                #pragma unroll
                for (int n = 0; n < 4; ++n)
                    acc[m][n] = __builtin_amdgcn_mfma_f32_16x16x32_bf16(
                        af[m], bf[n], acc[m][n], 0, 0, 0);
        }
        __syncthreads();
    }

    // epilogue: D col = lane&15, row = (lane>>4)*4 + r  (verified C/D layout)
    const int crow0 = row0 + wr * 64 + ((lane >> 4) << 2);
    const int ccol0 = col0 + wc * 64 + (lane & 15);
    #pragma unroll
    for (int n = 0; n < 4; ++n) {
        int col = ccol0 + n * 16;
        if (col < N) {
            float bv = bias[col];
            #pragma unroll
            for (int m = 0; m < 4; ++m) {
                #pragma unroll
                for (int r = 0; r < 4; ++r) {
                    C[(size_t)(crow0 + m * 16 + r) * N + col] = acc[m][n][r] + bv;
                }
            }
        }
    }
}

extern "C" void kernel_launch(void* const* d_in, const int* in_sizes, int n_in,
                              void* d_out, int out_size, void* d_ws, size_t ws_size,
                              hipStream_t stream)
{
    const float* x   = (const float*)d_in[0];
    const float* fs  = (const float*)d_in[1];
    const float* qw  = (const float*)d_in[2];
    const float* qw1 = (const float*)d_in[3];
    const float* qb1 = (const float*)d_in[4];
    const float* qw2 = (const float*)d_in[5];
    const float* qb2 = (const float*)d_in[6];
    const float* cw1 = (const float*)d_in[7];
    const float* cb1 = (const float*)d_in[8];
    const float* cw2 = (const float*)d_in[9];
    const float* cb2 = (const float*)d_in[10];
    const float* cw3 = (const float*)d_in[11];
    const float* cb3 = (const float*)d_in[12];

    float* q_logits = (float*)d_out;
    float* c_logits = q_logits + (size_t)BATCH * NCLS;
    float* qf_out   = c_logits + (size_t)BATCH * NCLS;

    __hip_bfloat16* hq   = (__hip_bfloat16*)d_ws;              // 8192 x 64   (1 MB)
    __hip_bfloat16* h2   = hq + (size_t)BATCH * 64;            // 8192 x 128  (2 MB)
    __hip_bfloat16* qw2t = h2 + (size_t)BATCH * 128;           // 3129 x 64   (0.4 MB)
    __hip_bfloat16* cw3t = qw2t + (size_t)NCLS * 64;           // 3129 x 128  (0.8 MB)

    transpose_cast<<<(64 * NCLS + 255) / 256, 256, 0, stream>>>(qw2, qw2t, 64, NCLS);
    transpose_cast<<<(128 * NCLS + 255) / 256, 256, 0, stream>>>(cw3, cw3t, 128, NCLS);

    quantum_kernel<<<BATCH / 4, 256, 0, stream>>>(x, fs, qw, qw1, qb1, qf_out, hq);
    chead_kernel<<<BATCH / 32, 256, 0, stream>>>(x, cw1, cb1, cw2, cb2, h2);

    dim3 grid((NCLS + 127) / 128, BATCH / 128);
    gemm_mfma<64><<<grid, 256, 0, stream>>>(hq, qw2t, qb2, q_logits, NCLS);
    gemm_mfma<128><<<grid, 256, 0, stream>>>(h2, cw3t, cb3, c_logits, NCLS);
}

// Round 3
// 167.891 us; speedup vs baseline: 1.7541x; 1.0148x over previous
//
#include <hip/hip_runtime.h>
#include <hip/hip_bf16.h>
#include <math.h>

#define NQ 7
#define NL 6
#define BATCH 8192
#define NPCA 32
#define NCLS 3129
#define NGATE 42

typedef __attribute__((ext_vector_type(8))) short short8;
typedef __attribute__((ext_vector_type(4))) float f32x4;

__device__ __forceinline__ void gload_lds16(const void* g, void* l) {
    __builtin_amdgcn_global_load_lds(
        (const __attribute__((address_space(1))) void*)g,
        (__attribute__((address_space(3))) void*)l, 16, 0, 0);
}

// ---------------------------------------------------------------------------
// Quantum circuit: one wave per sample, 2 complex amps per lane (registers).
// RY angles satisfy |th| <= (pi/2 + |w|)/2 < 1 rad -> hardware sin/cos
// (__sinf/__cosf, no range reduction). RZ phases precomputed per block.
// Fused: Z-expectations + q-head layer1 (relu(qf@W1+b1)) -> bf16.
// ---------------------------------------------------------------------------
__global__ __launch_bounds__(256) void quantum_kernel(
    const float* __restrict__ x,       // B x 32
    const float* __restrict__ fscale,  // 32
    const float* __restrict__ qw,      // 6 x 7 x 2
    const float* __restrict__ qh_w1,   // 7 x 64
    const float* __restrict__ qh_b1,   // 64
    float* __restrict__ qf_out,        // B x 7 (fp32, part of d_out)
    __hip_bfloat16* __restrict__ hq_out) // B x 64 bf16
{
    __shared__ float pzc[NGATE], pzs[NGATE], w0s[NGATE];
    int tid = threadIdx.x;
    if (tid < NGATE) {
        float t = qw[tid * 2 + 1] * 0.5f;
        float s, c;
        sincosf(t, &s, &c);               // once per block, keep libm
        pzs[tid] = s; pzc[tid] = c;
        w0s[tid] = qw[tid * 2 + 0];
    }
    __syncthreads();

    const int lane = tid & 63;
    const int wave = tid >> 6;
    const int sample = blockIdx.x * 4 + wave;

    float myfeat = 0.f;
    if (lane < NPCA) myfeat = atanf(x[sample * NPCA + lane] * fscale[lane]);

    float s0r = (lane == 0) ? 1.f : 0.f, s0i = 0.f, s1r = 0.f, s1i = 0.f;

    for (int layer = 0; layer < NL; ++layer) {
        for (int q = 0; q < NQ; ++q) {
            const int g = layer * NQ + q;
            const int b = NQ - 1 - q;
            float fv = (g < NPCA) ? __shfl(myfeat, g) : 0.f;
            float th = (fv + w0s[g]) * 0.5f;
            float s = __sinf(th), c = __cosf(th);   // |th| < 1 rad: HW trig safe
            if (b == 0) {
                float n0r = c * s0r - s * s1r, n0i = c * s0i - s * s1i;
                float n1r = s * s0r + c * s1r, n1i = s * s0i + c * s1i;
                s0r = n0r; s0i = n0i; s1r = n1r; s1i = n1i;
            } else {
                int m = 1 << (b - 1);
                float p0r = __shfl_xor(s0r, m), p0i = __shfl_xor(s0i, m);
                float p1r = __shfl_xor(s1r, m), p1i = __shfl_xor(s1i, m);
                if (((lane >> (b - 1)) & 1) == 0) {
                    s0r = c * s0r - s * p0r; s0i = c * s0i - s * p0i;
                    s1r = c * s1r - s * p1r; s1i = c * s1i - s * p1i;
                } else {
                    s0r = s * p0r + c * s0r; s0i = s * p0i + c * s0i;
                    s1r = s * p1r + c * s1r; s1i = s * p1i + c * s1i;
                }
            }
            float pc = pzc[g], ps = pzs[g];
            if (b == 0) {
                float t0 = pc * s0r + ps * s0i; s0i = pc * s0i - ps * s0r; s0r = t0;
                float t1 = pc * s1r - ps * s1i; s1i = pc * s1i + ps * s1r; s1r = t1;
            } else {
                float e = (((lane >> (b - 1)) & 1) == 0) ? ps : -ps;
                float t0 = pc * s0r + e * s0i; s0i = pc * s0i - e * s0r; s0r = t0;
                float t1 = pc * s1r + e * s1i; s1i = pc * s1i - e * s1r; s1r = t1;
            }
        }
        #pragma unroll
        for (int cq = 0; cq < NQ; ++cq) {
            if (cq == NQ - 1) {
                float r = __shfl_xor(s1r, 32), im = __shfl_xor(s1i, 32);
                s1r = r; s1i = im;
            } else if (cq == NQ - 2) {
                if (lane & 1) {
                    float tr = s0r; s0r = s1r; s1r = tr;
                    float ti = s0i; s0i = s1i; s1i = ti;
                }
            } else {
                const int bc = NQ - 1 - cq;
                const int bt = bc - 1;
                int m = 1 << (bt - 1);
                float p0r = __shfl_xor(s0r, m), p0i = __shfl_xor(s0i, m);
                float p1r = __shfl_xor(s1r, m), p1i = __shfl_xor(s1i, m);
                if ((lane >> (bc - 1)) & 1) {
                    s0r = p0r; s0i = p0i; s1r = p1r; s1i = p1i;
                }
            }
        }
    }

    float p0 = s0r * s0r + s0i * s0i;
    float p1 = s1r * s1r + s1i * s1i;
    float psum = p0 + p1;
    float qf[7];
    #pragma unroll
    for (int k = 0; k < 6; ++k)
        qf[k] = (((lane >> (5 - k)) & 1) ? -psum : psum);
    qf[6] = p0 - p1;
    #pragma unroll
    for (int off = 32; off >= 1; off >>= 1) {
        #pragma unroll
        for (int k = 0; k < 7; ++k) qf[k] += __shfl_xor(qf[k], off);
    }

    float acc = qh_b1[lane];
    #pragma unroll
    for (int k = 0; k < 7; ++k) acc += qf[k] * qh_w1[k * 64 + lane];
    hq_out[sample * 64 + lane] = __float2bfloat16(fmaxf(acc, 0.f));
    if (lane < 7) qf_out[sample * 7 + lane] = qf[lane];
}

// ---------------------------------------------------------------------------
// Classical head layers 1+2 fused -> h2 bf16.
// ---------------------------------------------------------------------------
__global__ __launch_bounds__(256) void chead_kernel(
    const float* __restrict__ x,    // B x 32
    const float* __restrict__ w1,   // 32 x 256
    const float* __restrict__ b1,   // 256
    const float* __restrict__ w2,   // 256 x 128
    const float* __restrict__ b2,   // 128
    __hip_bfloat16* __restrict__ h2out) // B x 128 bf16
{
    __shared__ float xs[32][36];
    __shared__ float h1s[32][260];
    const int tid = threadIdx.x;
    const int row0 = blockIdx.x * 32;

    for (int i = tid; i < 32 * 32; i += 256) {
        int r = i >> 5, k = i & 31;
        xs[r][k] = x[(row0 + r) * 32 + k];
    }
    __syncthreads();

    {
        float w1c[32];
        #pragma unroll
        for (int k = 0; k < 32; ++k) w1c[k] = w1[k * 256 + tid];
        float bb = b1[tid];
        for (int r = 0; r < 32; ++r) {
            float acc = bb;
            #pragma unroll
            for (int k = 0; k < 32; ++k) acc += xs[r][k] * w1c[k];
            h1s[r][tid] = fmaxf(acc, 0.f);
        }
    }
    __syncthreads();

    {
        const int c0 = (tid & 63) * 2;
        const int r0 = (tid >> 6) * 8;
        float accA[8], accB[8];
        float bbA = b2[c0], bbB = b2[c0 + 1];
        #pragma unroll
        for (int rr = 0; rr < 8; ++rr) { accA[rr] = bbA; accB[rr] = bbB; }
        for (int k = 0; k < 256; k += 4) {
            float hb[8][4];
            #pragma unroll
            for (int rr = 0; rr < 8; ++rr) {
                float4 h4 = *(const float4*)&h1s[r0 + rr][k];
                hb[rr][0] = h4.x; hb[rr][1] = h4.y; hb[rr][2] = h4.z; hb[rr][3] = h4.w;
            }
            #pragma unroll
            for (int j = 0; j < 4; ++j) {
                float2 w = *(const float2*)&w2[(k + j) * 128 + c0];
                #pragma unroll
                for (int rr = 0; rr < 8; ++rr) {
                    accA[rr] += hb[rr][j] * w.x;
                    accB[rr] += hb[rr][j] * w.y;
                }
            }
        }
        #pragma unroll
        for (int rr = 0; rr < 8; ++rr) {
            __hip_bfloat162 pr;
            pr.x = __float2bfloat16(fmaxf(accA[rr], 0.f));
            pr.y = __float2bfloat16(fmaxf(accB[rr], 0.f));
            *(__hip_bfloat162*)&h2out[(size_t)(row0 + r0 + rr) * 128 + c0] = pr;
        }
    }
}

// ---------------------------------------------------------------------------
// Weight prep: W (K x N fp32) -> Wt (N x K bf16), 64x64 LDS tile so both the
// global read (over n) and global write (over k) are coalesced.
// ---------------------------------------------------------------------------
__global__ __launch_bounds__(256) void transpose_cast(
    const float* __restrict__ W, __hip_bfloat16* __restrict__ Wt, int K, int N)
{
    __shared__ float tile[64][65];
    const int tid = threadIdx.x;
    const int n0 = blockIdx.x * 64;
    const int k0 = blockIdx.y * 64;

    #pragma unroll
    for (int i = 0; i < 16; ++i) {
        int id = tid + i * 256;
        int kr = id >> 6, nc = id & 63;
        int n = n0 + nc;
        tile[kr][nc] = (n < N) ? W[(size_t)(k0 + kr) * N + n] : 0.f;
    }
    __syncthreads();
    #pragma unroll
    for (int i = 0; i < 16; ++i) {
        int id = tid + i * 256;
        int nr = id >> 6, kc = id & 63;
        int n = n0 + nr;
        if (n < N) Wt[(size_t)n * K + k0 + kc] = __float2bfloat16(tile[kc][nr]);
    }
}

// ---------------------------------------------------------------------------
// MFMA GEMM: C(MxN) = A(MxK) @ Bt(NxK)^T + bias. 128x128 tile, 4 waves
// (each 64x64 = 4x4 fragments of 16x16). Staging via global_load_lds w=16:
// linear LDS dest, XOR-swizzled SOURCE chunk (c ^= r&7, self-inverse), same
// XOR on ds_read_b128 -> 2-way bank aliasing (free). B tail rows clamped to
// a valid source row: garbage only reaches output cols >= N (never written).
// ---------------------------------------------------------------------------
template <int K>
__global__ __launch_bounds__(256) void gemm_mfma(
    const __hip_bfloat16* __restrict__ A,   // M x K bf16
    const __hip_bfloat16* __restrict__ Bt,  // N x K bf16 (padded alloc >= 128-mult rows)
    const float* __restrict__ bias,         // N
    float* __restrict__ C,                  // M x N fp32
    int N)
{
    constexpr int KB = 64;                   // k per stage = 8 chunks of 8 bf16
    static_assert(K % KB == 0, "");
    __shared__ __hip_bfloat16 Alds[128 * KB];   // 16 KB, linear (id*8 elems)
    __shared__ __hip_bfloat16 Blds[128 * KB];   // 16 KB

    const int tid  = threadIdx.x;
    const int lane = tid & 63;
    const int wave = tid >> 6;
    const int wr = wave >> 1, wc = wave & 1;
    const int row0 = blockIdx.y * 128;
    const int col0 = blockIdx.x * 128;

    f32x4 acc[4][4] = {};

    for (int kb = 0; kb < K; kb += KB) {
        #pragma unroll
        for (int i = 0; i < 4; ++i) {
            int id = tid + i * 256;           // chunk 0..1023
            int r = id >> 3;                  // tile row 0..127
            int c = id & 7;                   // logical 16B chunk in row
            int cs = c ^ (r & 7);             // swizzled source chunk
            gload_lds16(&A[(size_t)(row0 + r) * K + kb + cs * 8], &Alds[id * 8]);
        }
        #pragma unroll
        for (int i = 0; i < 4; ++i) {
            int id = tid + i * 256;
            int r = id >> 3;
            int c = id & 7;
            int cs = c ^ (r & 7);
            int n = col0 + r;
            if (n >= N) n = N - 1;            // clamp: data garbage, col never written
            gload_lds16(&Bt[(size_t)n * K + kb + cs * 8], &Blds[id * 8]);
        }
        __syncthreads();                      // drains vmcnt before barrier

        const int frow = lane & 15;
        const int chi  = lane >> 4;           // 0..3
        #pragma unroll
        for (int kk = 0; kk < 2; ++kk) {      // chunk halves: 0..3 / 4..7
            short8 af[4], bf[4];
            #pragma unroll
            for (int m = 0; m < 4; ++m) {
                int r = wr * 64 + m * 16 + frow;
                int cs = (kk * 4 + chi) ^ (r & 7);
                af[m] = *(const short8*)&Alds[r * 64 + cs * 8];
            }
            #pragma unroll
            for (int n = 0; n < 4; ++n) {
                int r = wc * 64 + n * 16 + frow;
                int cs = (kk * 4 + chi) ^ (r & 7);
                bf[n] = *(const short8*)&Blds[r * 64 + cs * 8];
            }
            #pragma unroll
            for (int m = 0; m < 4; ++m)
                #pragma unroll
                for (int n = 0; n < 4; ++n)
                    acc[m][n] = __builtin_amdgcn_mfma_f32_16x16x32_bf16(
                        af[m], bf[n], acc[m][n], 0, 0, 0);
        }
        __syncthreads();
    }

    // epilogue: D col = lane&15, row = (lane>>4)*4 + r (verified C/D layout)
    const int crow0 = row0 + wr * 64 + ((lane >> 4) << 2);
    const int ccol0 = col0 + wc * 64 + (lane & 15);
    #pragma unroll
    for (int n = 0; n < 4; ++n) {
        int col = ccol0 + n * 16;
        if (col < N) {
            float bv = bias[col];
            #pragma unroll
            for (int m = 0; m < 4; ++m) {
                #pragma unroll
                for (int r = 0; r < 4; ++r) {
                    C[(size_t)(crow0 + m * 16 + r) * N + col] = acc[m][n][r] + bv;
                }
            }
        }
    }
}

extern "C" void kernel_launch(void* const* d_in, const int* in_sizes, int n_in,
                              void* d_out, int out_size, void* d_ws, size_t ws_size,
                              hipStream_t stream)
{
    const float* x   = (const float*)d_in[0];
    const float* fs  = (const float*)d_in[1];
    const float* qw  = (const float*)d_in[2];
    const float* qw1 = (const float*)d_in[3];
    const float* qb1 = (const float*)d_in[4];
    const float* qw2 = (const float*)d_in[5];
    const float* qb2 = (const float*)d_in[6];
    const float* cw1 = (const float*)d_in[7];
    const float* cb1 = (const float*)d_in[8];
    const float* cw2 = (const float*)d_in[9];
    const float* cb2 = (const float*)d_in[10];
    const float* cw3 = (const float*)d_in[11];
    const float* cb3 = (const float*)d_in[12];

    float* q_logits = (float*)d_out;
    float* c_logits = q_logits + (size_t)BATCH * NCLS;
    float* qf_out   = c_logits + (size_t)BATCH * NCLS;

    // ws layout (N padded to 3200 rows so clamped B-tile reads stay in-alloc)
    const int NPAD = 3200;
    __hip_bfloat16* hq   = (__hip_bfloat16*)d_ws;              // 8192 x 64
    __hip_bfloat16* h2   = hq + (size_t)BATCH * 64;            // 8192 x 128
    __hip_bfloat16* qw2t = h2 + (size_t)BATCH * 128;           // 3200 x 64
    __hip_bfloat16* cw3t = qw2t + (size_t)NPAD * 64;           // 3200 x 128

    {
        dim3 g1((NCLS + 63) / 64, 1);
        transpose_cast<<<g1, 256, 0, stream>>>(qw2, qw2t, 64, NCLS);
        dim3 g2((NCLS + 63) / 64, 2);
        transpose_cast<<<g2, 256, 0, stream>>>(cw3, cw3t, 128, NCLS);
    }

    quantum_kernel<<<BATCH / 4, 256, 0, stream>>>(x, fs, qw, qw1, qb1, qf_out, hq);
    chead_kernel<<<BATCH / 32, 256, 0, stream>>>(x, cw1, cb1, cw2, cb2, h2);

    dim3 grid((NCLS + 127) / 128, BATCH / 128);
    gemm_mfma<64><<<grid, 256, 0, stream>>>(hq, qw2t, qb2, q_logits, NCLS);
    gemm_mfma<128><<<grid, 256, 0, stream>>>(h2, cw3t, cb3, c_logits, NCLS);
}

// Round 4
// 115.062 us; speedup vs baseline: 2.5594x; 1.4591x over previous
//
#include <hip/hip_runtime.h>
#include <hip/hip_bf16.h>
#include <math.h>

#define NQ 7
#define NL 6
#define BATCH 8192
#define NPCA 32
#define NCLS 3129
#define NGATE 42

typedef __attribute__((ext_vector_type(8))) short short8;
typedef __attribute__((ext_vector_type(4))) float f32x4;

__device__ __forceinline__ void gload_lds16(const void* g, void* l) {
    __builtin_amdgcn_global_load_lds(
        (const __attribute__((address_space(1))) void*)g,
        (__attribute__((address_space(3))) void*)l, 16, 0, 0);
}

// ---------------------------------------------------------------------------
// Quantum circuit: one wave per sample, 2 complex amps per lane (registers).
// ---------------------------------------------------------------------------
__global__ __launch_bounds__(256) void quantum_kernel(
    const float* __restrict__ x,       // B x 32
    const float* __restrict__ fscale,  // 32
    const float* __restrict__ qw,      // 6 x 7 x 2
    const float* __restrict__ qh_w1,   // 7 x 64
    const float* __restrict__ qh_b1,   // 64
    float* __restrict__ qf_out,        // B x 7 (fp32, part of d_out)
    __hip_bfloat16* __restrict__ hq_out) // B x 64 bf16
{
    __shared__ float pzc[NGATE], pzs[NGATE], w0s[NGATE];
    int tid = threadIdx.x;
    if (tid < NGATE) {
        float t = qw[tid * 2 + 1] * 0.5f;
        float s, c;
        sincosf(t, &s, &c);
        pzs[tid] = s; pzc[tid] = c;
        w0s[tid] = qw[tid * 2 + 0];
    }
    __syncthreads();

    const int lane = tid & 63;
    const int wave = tid >> 6;
    const int sample = blockIdx.x * 4 + wave;

    float myfeat = 0.f;
    if (lane < NPCA) myfeat = atanf(x[sample * NPCA + lane] * fscale[lane]);

    float s0r = (lane == 0) ? 1.f : 0.f, s0i = 0.f, s1r = 0.f, s1i = 0.f;

    for (int layer = 0; layer < NL; ++layer) {
        for (int q = 0; q < NQ; ++q) {
            const int g = layer * NQ + q;
            const int b = NQ - 1 - q;
            float fv = (g < NPCA) ? __shfl(myfeat, g) : 0.f;
            float th = (fv + w0s[g]) * 0.5f;
            float s = __sinf(th), c = __cosf(th);   // |th| < 1 rad: HW trig safe
            if (b == 0) {
                float n0r = c * s0r - s * s1r, n0i = c * s0i - s * s1i;
                float n1r = s * s0r + c * s1r, n1i = s * s0i + c * s1i;
                s0r = n0r; s0i = n0i; s1r = n1r; s1i = n1i;
            } else {
                int m = 1 << (b - 1);
                float p0r = __shfl_xor(s0r, m), p0i = __shfl_xor(s0i, m);
                float p1r = __shfl_xor(s1r, m), p1i = __shfl_xor(s1i, m);
                if (((lane >> (b - 1)) & 1) == 0) {
                    s0r = c * s0r - s * p0r; s0i = c * s0i - s * p0i;
                    s1r = c * s1r - s * p1r; s1i = c * s1i - s * p1i;
                } else {
                    s0r = s * p0r + c * s0r; s0i = s * p0i + c * s0i;
                    s1r = s * p1r + c * s1r; s1i = s * p1i + c * s1i;
                }
            }
            float pc = pzc[g], ps = pzs[g];
            if (b == 0) {
                float t0 = pc * s0r + ps * s0i; s0i = pc * s0i - ps * s0r; s0r = t0;
                float t1 = pc * s1r - ps * s1i; s1i = pc * s1i + ps * s1r; s1r = t1;
            } else {
                float e = (((lane >> (b - 1)) & 1) == 0) ? ps : -ps;
                float t0 = pc * s0r + e * s0i; s0i = pc * s0i - e * s0r; s0r = t0;
                float t1 = pc * s1r + e * s1i; s1i = pc * s1i - e * s1r; s1r = t1;
            }
        }
        #pragma unroll
        for (int cq = 0; cq < NQ; ++cq) {
            if (cq == NQ - 1) {
                float r = __shfl_xor(s1r, 32), im = __shfl_xor(s1i, 32);
                s1r = r; s1i = im;
            } else if (cq == NQ - 2) {
                if (lane & 1) {
                    float tr = s0r; s0r = s1r; s1r = tr;
                    float ti = s0i; s0i = s1i; s1i = ti;
                }
            } else {
                const int bc = NQ - 1 - cq;
                const int bt = bc - 1;
                int m = 1 << (bt - 1);
                float p0r = __shfl_xor(s0r, m), p0i = __shfl_xor(s0i, m);
                float p1r = __shfl_xor(s1r, m), p1i = __shfl_xor(s1i, m);
                if ((lane >> (bc - 1)) & 1) {
                    s0r = p0r; s0i = p0i; s1r = p1r; s1i = p1i;
                }
            }
        }
    }

    float p0 = s0r * s0r + s0i * s0i;
    float p1 = s1r * s1r + s1i * s1i;
    float psum = p0 + p1;
    float qf[7];
    #pragma unroll
    for (int k = 0; k < 6; ++k)
        qf[k] = (((lane >> (5 - k)) & 1) ? -psum : psum);
    qf[6] = p0 - p1;
    #pragma unroll
    for (int off = 32; off >= 1; off >>= 1) {
        #pragma unroll
        for (int k = 0; k < 7; ++k) qf[k] += __shfl_xor(qf[k], off);
    }

    float acc = qh_b1[lane];
    #pragma unroll
    for (int k = 0; k < 7; ++k) acc += qf[k] * qh_w1[k * 64 + lane];
    hq_out[sample * 64 + lane] = __float2bfloat16(fmaxf(acc, 0.f));
    if (lane < 7) qf_out[sample * 7 + lane] = qf[lane];
}

// ---------------------------------------------------------------------------
// Classical head layers 1+2 fused -> h2 bf16. 16 rows/block (512 blocks,
// 2/CU), layer2: 2 rows x 4 cols per thread, float4 w2 loads.
// ---------------------------------------------------------------------------
__global__ __launch_bounds__(256) void chead_kernel(
    const float* __restrict__ x,    // B x 32
    const float* __restrict__ w1,   // 32 x 256
    const float* __restrict__ b1,   // 256
    const float* __restrict__ w2,   // 256 x 128
    const float* __restrict__ b2,   // 128
    __hip_bfloat16* __restrict__ h2out) // B x 128 bf16
{
    __shared__ float xs[16][33];
    __shared__ float h1s[16][260];
    const int tid = threadIdx.x;
    const int row0 = blockIdx.x * 16;

    for (int i = tid; i < 16 * 32; i += 256) {
        int r = i >> 5, k = i & 31;
        xs[r][k] = x[(row0 + r) * 32 + k];
    }
    __syncthreads();

    {
        float w1c[32];
        #pragma unroll
        for (int k = 0; k < 32; ++k) w1c[k] = w1[k * 256 + tid];
        float bb = b1[tid];
        #pragma unroll
        for (int r = 0; r < 16; ++r) {
            float a = bb;
            #pragma unroll
            for (int k = 0; k < 32; ++k) a += xs[r][k] * w1c[k];
            h1s[r][tid] = fmaxf(a, 0.f);
        }
    }
    __syncthreads();

    {
        const int c0 = (tid & 31) * 4;   // 0..124
        const int r0 = (tid >> 5) * 2;   // 0..14
        float4 bv = *(const float4*)&b2[c0];
        float a0[4] = {bv.x, bv.y, bv.z, bv.w};
        float a1[4] = {bv.x, bv.y, bv.z, bv.w};
        for (int k = 0; k < 256; k += 4) {
            float4 h0 = *(const float4*)&h1s[r0][k];
            float4 h1 = *(const float4*)&h1s[r0 + 1][k];
            #pragma unroll
            for (int j = 0; j < 4; ++j) {
                float4 w = *(const float4*)&w2[(size_t)(k + j) * 128 + c0];
                float hv0 = (j == 0) ? h0.x : (j == 1) ? h0.y : (j == 2) ? h0.z : h0.w;
                float hv1 = (j == 0) ? h1.x : (j == 1) ? h1.y : (j == 2) ? h1.z : h1.w;
                a0[0] += hv0 * w.x; a0[1] += hv0 * w.y; a0[2] += hv0 * w.z; a0[3] += hv0 * w.w;
                a1[0] += hv1 * w.x; a1[1] += hv1 * w.y; a1[2] += hv1 * w.z; a1[3] += hv1 * w.w;
            }
        }
        #pragma unroll
        for (int rr = 0; rr < 2; ++rr) {
            float* a = rr ? a1 : a0;
            __hip_bfloat162 q0, q1;
            q0.x = __float2bfloat16(fmaxf(a[0], 0.f));
            q0.y = __float2bfloat16(fmaxf(a[1], 0.f));
            q1.x = __float2bfloat16(fmaxf(a[2], 0.f));
            q1.y = __float2bfloat16(fmaxf(a[3], 0.f));
            size_t base = (size_t)(row0 + r0 + rr) * 128 + c0;
            *(__hip_bfloat162*)&h2out[base]     = q0;
            *(__hip_bfloat162*)&h2out[base + 2] = q1;
        }
    }
}

// ---------------------------------------------------------------------------
// Weight prep, both weights in one dispatch: y=0 -> qw2 (K=64);
// y=1,2 -> cw3 (K=128, k-chunk y-1). 64x64 LDS transpose tile.
// ---------------------------------------------------------------------------
__global__ __launch_bounds__(256) void transpose_cast2(
    const float* __restrict__ Wq, __hip_bfloat16* __restrict__ Wqt,
    const float* __restrict__ Wc, __hip_bfloat16* __restrict__ Wct, int N)
{
    __shared__ float tile[64][65];
    const int tid = threadIdx.x;
    const int n0 = blockIdx.x * 64;
    const float* W; __hip_bfloat16* Wt; int K, k0;
    if (blockIdx.y == 0) { W = Wq; Wt = Wqt; K = 64;  k0 = 0; }
    else                 { W = Wc; Wt = Wct; K = 128; k0 = (blockIdx.y - 1) * 64; }

    #pragma unroll
    for (int i = 0; i < 16; ++i) {
        int id = tid + i * 256;
        int kr = id >> 6, nc = id & 63;
        int n = n0 + nc;
        tile[kr][nc] = (n < N) ? W[(size_t)(k0 + kr) * N + n] : 0.f;
    }
    __syncthreads();
    #pragma unroll
    for (int i = 0; i < 16; ++i) {
        int id = tid + i * 256;
        int nr = id >> 6, kc = id & 63;
        int n = n0 + nr;
        if (n < N) Wt[(size_t)n * K + k0 + kc] = __float2bfloat16(tile[kc][nr]);
    }
}

// ---------------------------------------------------------------------------
// Dual MFMA GEMM (z=0: K=64 q-head; z=1: K=128 c-head). 128x128 tile, 4 waves.
// Staging: global_load_lds w=16, linear LDS dest, XOR-swizzled source chunk
// (c ^= r&7), same XOR on ds_read_b128. Epilogue: acc staged through LDS
// (reusing the 32KB staging buffer), then full-wave contiguous dword stores
// (64 lanes x consecutive cols = 256B/instr), bias cached per thread.
// ---------------------------------------------------------------------------
__global__ __launch_bounds__(256) void gemm_mfma_dual(
    const __hip_bfloat16* __restrict__ A0, const __hip_bfloat16* __restrict__ B0,
    const float* __restrict__ bias0, float* __restrict__ C0,
    const __hip_bfloat16* __restrict__ A1, const __hip_bfloat16* __restrict__ B1,
    const float* __restrict__ bias1, float* __restrict__ C1, int N)
{
    __shared__ alignas(16) unsigned char shraw[32768];
    __hip_bfloat16* Alds = (__hip_bfloat16*)shraw;           // 128 x 64 (16 KB)
    __hip_bfloat16* Blds = Alds + 128 * 64;                  // 128 x 64 (16 KB)
    float* scr = (float*)shraw;                              // 64 x 128 fp32 (32 KB)

    const int z = blockIdx.z;
    const __hip_bfloat16* A  = z ? A1 : A0;
    const __hip_bfloat16* Bt = z ? B1 : B0;
    const float* bias        = z ? bias1 : bias0;
    float* C                 = z ? C1 : C0;
    const int K              = z ? 128 : 64;

    const int tid  = threadIdx.x;
    const int lane = tid & 63;
    const int wave = tid >> 6;
    const int wr = wave >> 1, wc = wave & 1;
    const int row0 = blockIdx.y * 128;
    const int col0 = blockIdx.x * 128;

    f32x4 acc[4][4] = {};

    for (int kb = 0; kb < K; kb += 64) {
        #pragma unroll
        for (int i = 0; i < 4; ++i) {
            int id = tid + i * 256;           // chunk 0..1023
            int r = id >> 3;                  // tile row 0..127
            int c = id & 7;
            int cs = c ^ (r & 7);             // swizzled source chunk
            gload_lds16(&A[(size_t)(row0 + r) * K + kb + cs * 8], &Alds[id * 8]);
        }
        #pragma unroll
        for (int i = 0; i < 4; ++i) {
            int id = tid + i * 256;
            int r = id >> 3;
            int c = id & 7;
            int cs = c ^ (r & 7);
            int n = col0 + r;
            if (n >= N) n = N - 1;            // clamp: garbage cols never stored
            gload_lds16(&Bt[(size_t)n * K + kb + cs * 8], &Blds[id * 8]);
        }
        __syncthreads();                      // drains vmcnt before barrier

        const int frow = lane & 15;
        const int chi  = lane >> 4;
        #pragma unroll
        for (int kk = 0; kk < 2; ++kk) {
            short8 af[4], bf[4];
            #pragma unroll
            for (int m = 0; m < 4; ++m) {
                int r = wr * 64 + m * 16 + frow;
                int cs = (kk * 4 + chi) ^ (r & 7);
                af[m] = *(const short8*)&Alds[r * 64 + cs * 8];
            }
            #pragma unroll
            for (int n = 0; n < 4; ++n) {
                int r = wc * 64 + n * 16 + frow;
                int cs = (kk * 4 + chi) ^ (r & 7);
                bf[n] = *(const short8*)&Blds[r * 64 + cs * 8];
            }
            #pragma unroll
            for (int m = 0; m < 4; ++m)
                #pragma unroll
                for (int n = 0; n < 4; ++n)
                    acc[m][n] = __builtin_amdgcn_mfma_f32_16x16x32_bf16(
                        af[m], bf[n], acc[m][n], 0, 0, 0);
        }
        __syncthreads();
    }

    // ---- epilogue: 2 passes of 64 rows x 128 cols through LDS ----
    const int g = lane >> 4;        // row sub-group
    const int fcol = lane & 15;
    const int ccr = tid & 127;      // per-thread output column (constant)
    const int bc  = col0 + ccr;
    const float bv = (bc < N) ? bias[bc] : 0.f;

    #pragma unroll
    for (int p = 0; p < 2; ++p) {
        if (p) __syncthreads();     // previous pass's reads done
        #pragma unroll
        for (int mm = 0; mm < 2; ++mm) {
            #pragma unroll
            for (int n = 0; n < 4; ++n) {
                int rl = wr * 32 + mm * 16 + g * 4;
                int cc = wc * 64 + n * 16 + fcol;
                int ccs = cc ^ (((rl >> 2) & 1) << 4);   // 2-way banking max
                #pragma unroll
                for (int r = 0; r < 4; ++r)
                    scr[(rl + r) * 128 + ccs] = acc[2 * p + mm][n][r];
            }
        }
        __syncthreads();
        if (bc < N) {
            #pragma unroll
            for (int i = 0; i < 32; ++i) {
                int id = i * 256 + tid;
                int rl = id >> 7;                         // 0..63
                int ccs = ccr ^ (((rl >> 2) & 1) << 4);
                int grow = row0 + p * 32 + ((rl >> 5) << 6) + (rl & 31);
                C[(size_t)grow * N + bc] = scr[rl * 128 + ccs] + bv;
            }
        }
    }
}

extern "C" void kernel_launch(void* const* d_in, const int* in_sizes, int n_in,
                              void* d_out, int out_size, void* d_ws, size_t ws_size,
                              hipStream_t stream)
{
    const float* x   = (const float*)d_in[0];
    const float* fs  = (const float*)d_in[1];
    const float* qw  = (const float*)d_in[2];
    const float* qw1 = (const float*)d_in[3];
    const float* qb1 = (const float*)d_in[4];
    const float* qw2 = (const float*)d_in[5];
    const float* qb2 = (const float*)d_in[6];
    const float* cw1 = (const float*)d_in[7];
    const float* cb1 = (const float*)d_in[8];
    const float* cw2 = (const float*)d_in[9];
    const float* cb2 = (const float*)d_in[10];
    const float* cw3 = (const float*)d_in[11];
    const float* cb3 = (const float*)d_in[12];

    float* q_logits = (float*)d_out;
    float* c_logits = q_logits + (size_t)BATCH * NCLS;
    float* qf_out   = c_logits + (size_t)BATCH * NCLS;

    const int NPAD = 3200;
    __hip_bfloat16* hq   = (__hip_bfloat16*)d_ws;              // 8192 x 64
    __hip_bfloat16* h2   = hq + (size_t)BATCH * 64;            // 8192 x 128
    __hip_bfloat16* qw2t = h2 + (size_t)BATCH * 128;           // 3200 x 64
    __hip_bfloat16* cw3t = qw2t + (size_t)NPAD * 64;           // 3200 x 128

    dim3 tg((NCLS + 63) / 64, 3);
    transpose_cast2<<<tg, 256, 0, stream>>>(qw2, qw2t, cw3, cw3t, NCLS);

    quantum_kernel<<<BATCH / 4, 256, 0, stream>>>(x, fs, qw, qw1, qb1, qf_out, hq);
    chead_kernel<<<BATCH / 16, 256, 0, stream>>>(x, cw1, cb1, cw2, cb2, h2);

    dim3 grid((NCLS + 127) / 128, BATCH / 128, 2);
    gemm_mfma_dual<<<grid, 256, 0, stream>>>(hq, qw2t, qb2, q_logits,
                                             h2, cw3t, cb3, c_logits, NCLS);
}